// Round 8
// baseline (266.540 us; speedup 1.0000x reference)
//
#include <hip/hip_runtime.h>

// Problem constants
#define BB    2
#define HN    8
#define NSEQ  2048
#define DIMM  1536
#define DKD   64
#define DVD   192
#define QCOLS 512        // HN*DKD
#define VCOLS 1536       // HN*DVD

typedef short short8 __attribute__((ext_vector_type(8)));
typedef float f32x4  __attribute__((ext_vector_type(4)));
typedef unsigned short ushortT;

static __device__ inline ushortT f2bf(float f) {
    unsigned u = __builtin_bit_cast(unsigned, f);
    u = (u + 0x7FFFu + ((u >> 16) & 1u)) >> 16;
    return (ushortT)u;
}

// async global -> LDS, 16B per lane. LDS dest = wave-uniform base + lane*16.
static __device__ inline void gl_lds16(const ushortT* g, ushortT* l) {
    __builtin_amdgcn_global_load_lds(
        (const __attribute__((address_space(1))) unsigned int*)g,
        (__attribute__((address_space(3))) unsigned int*)l, 16, 0, 0);
}

// HW waitcnt + COMPILER memory fence in one (builtin s_waitcnt is IntrNoMem ->
// not a fence; asm "memory" clobber blocks code motion AND emits the wait).
#define FENCE_VM12()   asm volatile("s_waitcnt vmcnt(12)" ::: "memory")
#define FENCE_VM4()    asm volatile("s_waitcnt vmcnt(4)" ::: "memory")
#define FENCE_LGKM0()  asm volatile("s_waitcnt lgkmcnt(0)" ::: "memory")
#define FENCE_SOFT()   asm volatile("" ::: "memory")

#if __has_builtin(__builtin_amdgcn_exp2f)
#define EXP2(x) __builtin_amdgcn_exp2f(x)
#else
#define EXP2(x) exp2f(x)
#endif

#define LOG2E 1.44269504f

// ---------------------------------------------------------------------------
// Prep (single launch): region-decoded by blockIdx.x  (unchanged)
// ---------------------------------------------------------------------------
__global__ __launch_bounds__(256)
void prep_kernel(const float* __restrict__ x,
                 const float* __restrict__ Wq, const float* __restrict__ Wk,
                 const float* __restrict__ Wv, const float* __restrict__ Wo,
                 ushortT* __restrict__ xb, ushortT* __restrict__ wqkv,
                 ushortT* __restrict__ wo_t)
{
    __shared__ ushortT tt[32][33];
    const int b = blockIdx.x, tid = threadIdx.x;

    if (b < 3072) {
        const size_t idx = (size_t)b * 256 + tid;
        const float4* p = (const float4*)x + idx * 2;
        const float4 a = p[0], c = p[1];
        short8 v;
        v[0] = f2bf(a.x); v[1] = f2bf(a.y); v[2] = f2bf(a.z); v[3] = f2bf(a.w);
        v[4] = f2bf(c.x); v[5] = f2bf(c.y); v[6] = f2bf(c.z); v[7] = f2bf(c.w);
        *(short8*)(xb + idx * 8) = v;
        return;
    }

    const float* W; ushortT* Wt; int ncols, t;
    if (b < 3840)      { W = Wq; Wt = wqkv;                          ncols = QCOLS; t = b - 3072; }
    else if (b < 4608) { W = Wk; Wt = wqkv + (size_t)QCOLS * DIMM;   ncols = QCOLS; t = b - 3840; }
    else if (b < 6912) { W = Wv; Wt = wqkv + (size_t)2*QCOLS * DIMM; ncols = VCOLS; t = b - 4608; }
    else               { W = Wo; Wt = wo_t;                          ncols = DIMM;  t = b - 6912; }

    const int nbx = ncols >> 5;
    const int c0 = (t % nbx) * 32, k0 = (t / nbx) * 32;
    const int lx = tid & 31, ly = tid >> 5;
    #pragma unroll
    for (int r = 0; r < 4; r++)
        tt[ly + r * 8][lx] = f2bf(W[(size_t)(k0 + ly + r * 8) * ncols + c0 + lx]);
    __syncthreads();
    #pragma unroll
    for (int r = 0; r < 4; r++)
        Wt[(size_t)(c0 + ly + r * 8) * DIMM + k0 + lx] = tt[lx][ly + r * 8];
}

// ---------------------------------------------------------------------------
// GEMM (structure unchanged from R4; q epilogue now folds log2e so the flash
// softmax can use native v_exp_f32 = 2^x without a multiply)
// ---------------------------------------------------------------------------
__global__ __launch_bounds__(256)
void gemm_kernel(const ushortT* __restrict__ A, const ushortT* __restrict__ Bt,
                 const float* __restrict__ bo,
                 const float* __restrict__ pos, const float* __restrict__ rcb,
                 ushortT* __restrict__ q_ws, ushortT* __restrict__ k_ws,
                 ushortT* __restrict__ v_ws, float* __restrict__ Cout, int mode)
{
    __shared__ ushortT As[128 * 64];   // 16 KB
    __shared__ ushortT Bs[64 * 64];    //  8 KB

    const int tid  = threadIdx.x;
    const int wave = tid >> 6, lane = tid & 63;
    const int quad = lane >> 4, l15 = lane & 15;
    const int m0 = blockIdx.y * 128, n0 = blockIdx.x * 64;

    const int sl_r = lane >> 3;
    const int sl_c = ((lane & 7) ^ sl_r) * 8;

    const ushortT* Ab = A  + (size_t)m0 * DIMM;
    const ushortT* Bb = Bt + (size_t)n0 * DIMM;

    f32x4 acc[2][4];
    #pragma unroll
    for (int i = 0; i < 2; i++)
        #pragma unroll
        for (int j = 0; j < 4; j++) acc[i][j] = (f32x4){0.f, 0.f, 0.f, 0.f};

    for (int k0 = 0; k0 < DIMM; k0 += 64) {
        #pragma unroll
        for (int t = 0; t < 4; t++) {
            const int g = wave * 4 + t;
            gl_lds16(Ab + (size_t)(g * 8 + sl_r) * DIMM + k0 + sl_c, &As[g * 512]);
        }
        #pragma unroll
        for (int t = 0; t < 2; t++) {
            const int g = wave * 2 + t;
            gl_lds16(Bb + (size_t)(g * 8 + sl_r) * DIMM + k0 + sl_c, &Bs[g * 512]);
        }
        __syncthreads();

        short8 af[2][2], bf[4][2];
        #pragma unroll
        for (int i = 0; i < 2; i++) {
            const int r = wave * 32 + i * 16 + l15;
            #pragma unroll
            for (int ks = 0; ks < 2; ks++)
                af[i][ks] = *(const short8*)&As[r * 64 + ((ks * 4 + quad) ^ (l15 & 7)) * 8];
        }
        #pragma unroll
        for (int j = 0; j < 4; j++) {
            const int r = j * 16 + l15;
            #pragma unroll
            for (int ks = 0; ks < 2; ks++)
                bf[j][ks] = *(const short8*)&Bs[r * 64 + ((ks * 4 + quad) ^ (l15 & 7)) * 8];
        }

        #pragma unroll
        for (int ks = 0; ks < 2; ks++)
            #pragma unroll
            for (int i = 0; i < 2; i++)
                #pragma unroll
                for (int j = 0; j < 4; j++)
                    acc[i][j] = __builtin_amdgcn_mfma_f32_16x16x32_bf16(af[i][ks], bf[j][ks], acc[i][j], 0, 0, 0);

        __syncthreads();
    }

    #pragma unroll
    for (int i = 0; i < 2; i++) {
        #pragma unroll
        for (int j = 0; j < 4; j++) {
            const int gcol = n0 + j * 16 + l15;
            #pragma unroll
            for (int r = 0; r < 4; r++) {
                const int grow = m0 + wave * 32 + i * 16 + quad * 4 + r;
                const float val = acc[i][j][r];
                if (mode == 1) {
                    Cout[(size_t)grow * DIMM + gcol] = val + bo[gcol];
                } else {
                    const int b = grow >> 11, n = grow & (NSEQ - 1);
                    if (gcol < QCOLS) {
                        const int h = gcol >> 6, d = gcol & 63;
                        // log2e folded in: flash softmax runs in exp2 domain
                        q_ws[((size_t)(b * HN + h) * NSEQ + n) * DKD + d] =
                            f2bf((val * 0.125f + pos[((size_t)h * NSEQ + n) * DKD + d] + rcb[h * DKD + d]) * LOG2E);
                    } else if (gcol < 2 * QCOLS) {
                        const int c = gcol - QCOLS, h = c >> 6, d = c & 63;
                        k_ws[((size_t)(b * HN + h) * NSEQ + n) * DKD + d] = f2bf(val);
                    } else {
                        const int c = gcol - 2 * QCOLS, h = c / DVD, d = c - h * DVD;
                        v_ws[((size_t)(b * HN + h) * DVD + d) * NSEQ + n] = f2bf(val);   // [b,h,d,key]
                    }
                }
            }
        }
    }
}

// ---------------------------------------------------------------------------
// Flash v3: cross-round prefetch, single-buffered (AITER-style: loads stay in
// flight across the round boundary; never a cold vmcnt(0)).
// Per round r: vmcnt(12)[K_r landed] -> QK -> lgkm0 -> issue K_{r+1} ->
// exp2/P(swizzled) -> vmcnt(4)[V_r landed, K_{r+1} in flight] -> vf reads ->
// lgkm0 -> issue V_{r+1} -> PV MFMAs on registers while r+1 flies.
// Wrapped prefetch keeps vmcnt counts uniform; epilogue __syncthreads drains.
// P LDS swizzle chunk^quad: write = 32 banks x 2-way = conflict-free.
// ---------------------------------------------------------------------------
#define PLD2 40
#define SHIFT2 28.8539008f    // 20*log2e; arbitrary uniform shift, cancels in 1/l

__global__ __launch_bounds__(128)
void flash_kernel(const ushortT* __restrict__ q_ws, const ushortT* __restrict__ k_ws,
                  const ushortT* __restrict__ v_ws, ushortT* __restrict__ attn)
{
    // [0,16384): per-wave staging (wave*8192: K 2048 shorts, V 6144 shorts)
    // [16384,18944): P buffers (wave*32*PLD2); reused for O/l exchange at end
    __shared__ ushortT lds[16384 + 2 * 32 * PLD2];

    const int tid = threadIdx.x;
    const int wave = tid >> 6, lane = tid & 63;
    const int quad = lane >> 4, l15 = lane & 15;

    const int bh = blockIdx.x & 15;        // XCD-affine: bh's blocks share L2
    const int qt = blockIdx.x >> 4;
    const int n0 = qt * 32;
    const int b  = bh >> 3, h = bh & 7;

    const ushortT* kg = k_ws + (size_t)bh * NSEQ * DKD + (size_t)(wave * 1024) * DKD;
    const ushortT* vg = v_ws + (size_t)bh * DVD * NSEQ + wave * 1024;

    ushortT* st = lds + wave * 8192;           // K at [0,2048), V at [2048,8192)
    ushortT* Pw = lds + 16384 + wave * (32 * PLD2);

    // staging source swizzles
    const int k_r = lane >> 3, k_c = ((lane & 7) ^ (k_r & 7)) * 8;   // K: 8 rows x 8 chunks
    const int v_r = lane >> 2, v_c = ((lane & 3) ^ (v_r & 3)) * 8;   // V: 16 rows x 4 chunks

    // Q A-frags (resident): qf[mt][ks], rows n0 + mt*16 + l15
    short8 qf[2][2];
    #pragma unroll
    for (int mt = 0; mt < 2; mt++)
        #pragma unroll
        for (int ks = 0; ks < 2; ks++)
            qf[mt][ks] = *(const short8*)(q_ws + ((size_t)bh * NSEQ + n0 + mt * 16 + l15) * DKD + ks * 32 + quad * 8);

    f32x4 o[2][12];
    #pragma unroll
    for (int mt = 0; mt < 2; mt++)
        #pragma unroll
        for (int nt = 0; nt < 12; nt++) o[mt][nt] = (f32x4){0.f, 0.f, 0.f, 0.f};

    float l_part[2][4];
    #pragma unroll
    for (int mt = 0; mt < 2; mt++)
        #pragma unroll
        for (int i = 0; i < 4; i++) l_part[mt][i] = 0.f;

    // ---- prologue: stage round 0 (K first: the 4 oldest vmcnt entries) ----
    #pragma unroll
    for (int t = 0; t < 4; t++)
        gl_lds16(kg + (size_t)(t * 8 + k_r) * DKD + k_c, st + t * 512);
    #pragma unroll
    for (int u = 0; u < 12; u++)
        gl_lds16(vg + (size_t)(u * 16 + v_r) * NSEQ + v_c, st + 2048 + u * 512);

    for (int kt0 = 0; kt0 < 1024; kt0 += 32) {
        const int ktn = (kt0 + 32) & 1023;   // wrapped prefetch target (round 31: dummy)

        FENCE_VM12();  // K_r landed (outstanding 16 -> leaves V_r's 12)

        // ---- S = Q @ K^T ----
        f32x4 s[2][2];
        #pragma unroll
        for (int mt = 0; mt < 2; mt++)
            #pragma unroll
            for (int nt = 0; nt < 2; nt++) s[mt][nt] = (f32x4){0.f, 0.f, 0.f, 0.f};
        #pragma unroll
        for (int ks = 0; ks < 2; ks++)
            #pragma unroll
            for (int nt = 0; nt < 2; nt++) {
                const int key = nt * 16 + l15;
                short8 kf = *(const short8*)&st[key * 64 + (((ks * 4 + quad) ^ (key & 7)) * 8)];
                s[0][nt] = __builtin_amdgcn_mfma_f32_16x16x32_bf16(qf[0][ks], kf, s[0][nt], 0, 0, 0);
                s[1][nt] = __builtin_amdgcn_mfma_f32_16x16x32_bf16(qf[1][ks], kf, s[1][nt], 0, 0, 0);
            }

        FENCE_LGKM0();  // kf reads retired -> K region reusable
        #pragma unroll
        for (int t = 0; t < 4; t++)      // prefetch K_{r+1}
            gl_lds16(kg + (size_t)(ktn + t * 8 + k_r) * DKD + k_c, st + t * 512);

        // ---- p = 2^(s' - SHIFT2); partial sums; P write (swizzled, 2-way) ----
        #pragma unroll
        for (int mt = 0; mt < 2; mt++)
            #pragma unroll
            for (int nt = 0; nt < 2; nt++)
                #pragma unroll
                for (int i = 0; i < 4; i++) {
                    const float p = EXP2(s[mt][nt][i] - SHIFT2);
                    l_part[mt][i] += p;
                    const int row = mt * 16 + quad * 4 + i;
                    const int ch  = (nt * 2 + (l15 >> 3)) ^ quad;   // chunk^quad swizzle
                    Pw[row * PLD2 + ch * 8 + (l15 & 7)] = f2bf(p);
                }

        FENCE_SOFT();  // keep P writes above P reads (cross-lane dep)

        short8 a[2];
        #pragma unroll
        for (int mt = 0; mt < 2; mt++) {
            const int row = mt * 16 + l15;
            a[mt] = *(const short8*)&Pw[row * PLD2 + ((quad ^ ((l15 >> 2) & 3)) * 8)];
        }

        FENCE_VM4();   // V_r landed (leaves K_{r+1}'s 4 in flight)

        short8 vf[12];
        #pragma unroll
        for (int nt2 = 0; nt2 < 12; nt2++) {
            const int d = nt2 * 16 + l15;
            vf[nt2] = *(const short8*)&st[2048 + d * 32 + ((quad ^ (d & 3)) * 8)];
        }

        FENCE_LGKM0();  // vf/P reads retired -> V region reusable
        #pragma unroll
        for (int u = 0; u < 12; u++)     // prefetch V_{r+1}
            gl_lds16(vg + (size_t)(u * 16 + v_r) * NSEQ + ktn + v_c, st + 2048 + u * 512);

        // ---- O += P @ V (registers only; r+1 loads in flight) ----
        #pragma unroll
        for (int nt2 = 0; nt2 < 12; nt2++) {
            o[0][nt2] = __builtin_amdgcn_mfma_f32_16x16x32_bf16(a[0], vf[nt2], o[0][nt2], 0, 0, 0);
            o[1][nt2] = __builtin_amdgcn_mfma_f32_16x16x32_bf16(a[1], vf[nt2], o[1][nt2], 0, 0, 0);
        }
    }

    // ---- reduce l over the 16 key-lanes ----
    #pragma unroll
    for (int off = 1; off <= 8; off <<= 1)
        #pragma unroll
        for (int mt = 0; mt < 2; mt++)
            #pragma unroll
            for (int i = 0; i < 4; i++)
                l_part[mt][i] += __shfl_xor(l_part[mt][i], off, 64);

    // ---- combine key-half partials in LDS; wave 0 finalizes ----
    __syncthreads();   // also drains the dangling round-31 prefetch (vmcnt 0)
    float* ox = (float*)lds;              // 96 slots x 64 lanes
    float* lx = (float*)(lds + 16384);    // 8 slots x 64 lanes
    if (wave == 1) {
        #pragma unroll
        for (int mt = 0; mt < 2; mt++)
            #pragma unroll
            for (int nt2 = 0; nt2 < 12; nt2++)
                #pragma unroll
                for (int i = 0; i < 4; i++)
                    ox[(((mt * 12 + nt2) * 4 + i) * 64) + lane] = o[mt][nt2][i];
        #pragma unroll
        for (int mt = 0; mt < 2; mt++)
            #pragma unroll
            for (int i = 0; i < 4; i++)
                lx[(mt * 4 + i) * 64 + lane] = l_part[mt][i];
    }
    __syncthreads();
    if (wave == 0) {
        float inv[2][4];
        #pragma unroll
        for (int mt = 0; mt < 2; mt++)
            #pragma unroll
            for (int i = 0; i < 4; i++)
                inv[mt][i] = 1.f / (l_part[mt][i] + lx[(mt * 4 + i) * 64 + lane]);
        #pragma unroll
        for (int mt = 0; mt < 2; mt++)
            #pragma unroll
            for (int nt2 = 0; nt2 < 12; nt2++)
                #pragma unroll
                for (int i = 0; i < 4; i++) {
                    const float v = o[mt][nt2][i] + ox[(((mt * 12 + nt2) * 4 + i) * 64) + lane];
                    const int n = n0 + mt * 16 + quad * 4 + i;
                    attn[((size_t)b * NSEQ + n) * DIMM + h * DVD + nt2 * 16 + l15] =
                        f2bf(v * inv[mt][i]);
                }
    }
}

// ---------------------------------------------------------------------------
extern "C" void kernel_launch(void* const* d_in, const int* in_sizes, int n_in,
                              void* d_out, int out_size, void* d_ws, size_t ws_size,
                              hipStream_t stream)
{
    const float* x   = (const float*)d_in[0];
    const float* Wq  = (const float*)d_in[1];
    const float* Wk  = (const float*)d_in[2];
    const float* Wv  = (const float*)d_in[3];
    const float* Wo  = (const float*)d_in[4];
    const float* bo  = (const float*)d_in[5];
    const float* pos = (const float*)d_in[6];
    const float* rcb = (const float*)d_in[7];
    float* out = (float*)d_out;

    ushortT* xb    = (ushortT*)d_ws;                             // 4096*1536
    ushortT* wqkv  = xb    + (size_t)4096 * DIMM;                // 2560*1536
    ushortT* wo_t  = wqkv  + (size_t)(2 * QCOLS + VCOLS) * DIMM; // 1536*1536
    ushortT* q_ws  = wo_t  + (size_t)DIMM * DIMM;
    ushortT* k_ws  = q_ws  + (size_t)BB * HN * NSEQ * DKD;
    ushortT* v_ws  = k_ws  + (size_t)BB * HN * NSEQ * DKD;       // V^T [b,h,d,key]
    ushortT* attnb = v_ws  + (size_t)BB * HN * NSEQ * DVD;       // 4096*1536

    prep_kernel<<<dim3(9216), dim3(256), 0, stream>>>(x, Wq, Wk, Wv, Wo, xb, wqkv, wo_t);

    gemm_kernel<<<dim3(40, 32), dim3(256), 0, stream>>>(xb, wqkv, bo, pos, rcb,
                                                        q_ws, k_ws, v_ws, nullptr, 0);
    flash_kernel<<<dim3(1024), dim3(128), 0, stream>>>(q_ws, k_ws, v_ws, attnb);
    gemm_kernel<<<dim3(24, 32), dim3(256), 0, stream>>>(attnb, wo_t, bo, pos, rcb,
                                                        q_ws, k_ws, v_ws, out, 1);
}